// Round 10
// baseline (1172.132 us; speedup 1.0000x reference)
//
#include <hip/hip_runtime.h>

#define HID 128
#define LDP 136   // padded LDS row stride in bf16 elems (272 B)

typedef short s16x8 __attribute__((ext_vector_type(8)));
typedef float f32x4 __attribute__((ext_vector_type(4)));

__device__ __forceinline__ float bf2f(unsigned int u) {
  union { unsigned int i; float f; } v; v.i = u << 16; return v.f;
}
__device__ __forceinline__ float asf(unsigned int u) {
  union { unsigned int i; float f; } v; v.i = u; return v.f;
}
__device__ __forceinline__ unsigned short f2bf(float f) {
  union { float f; unsigned int i; } v; v.f = f;
  unsigned int r = v.i + 0x7fffu + ((v.i >> 16) & 1u);
  return (unsigned short)(r >> 16);
}

// ---------------- zero fill (vectorized) ----------------
__global__ void k_zero4(float4* __restrict__ p, size_t n4) {
  size_t i = (size_t)blockIdx.x * blockDim.x + threadIdx.x;
  if (i < n4) p[i] = (float4){0.f, 0.f, 0.f, 0.f};
}

// ---------------- counting sort ----------------
__global__ void k_hist(const int* __restrict__ dst, int* __restrict__ deg, int nE) {
  int e = blockIdx.x * blockDim.x + threadIdx.x;
  if (e < nE) atomicAdd(&deg[dst[e]], 1);
}

__global__ void k_scanA(const int* __restrict__ deg, int* __restrict__ bsum) {
  __shared__ int ss[256];
  int t = threadIdx.x;
  ss[t] = deg[blockIdx.x * 256 + t];
  __syncthreads();
  for (int off = 128; off; off >>= 1) {
    if (t < off) ss[t] += ss[t + off];
    __syncthreads();
  }
  if (t == 0) bsum[blockIdx.x] = ss[0];
}

__global__ void k_scanB(const int* __restrict__ bsum, int* __restrict__ bsumx, int NB) {
  __shared__ int sd[512];
  int t = threadIdx.x;
  int v = (t < NB) ? bsum[t] : 0;
  sd[t] = v;
  __syncthreads();
  for (int off = 1; off < 512; off <<= 1) {
    int a = (t >= off) ? sd[t - off] : 0;
    __syncthreads();
    sd[t] += a;
    __syncthreads();
  }
  if (t < NB) bsumx[t] = sd[t] - v;
}

// writes exclusive scan to BOTH cursor (mutated by scatter) and rowptr (kept)
__global__ void k_scanC(const int* __restrict__ deg, const int* __restrict__ bsumx,
                        int* __restrict__ cursor, int* __restrict__ rowptr) {
  __shared__ int ss[256];
  int t = threadIdx.x, i = blockIdx.x * 256 + t;
  int v = deg[i];
  ss[t] = v;
  __syncthreads();
  for (int off = 1; off < 256; off <<= 1) {
    int a = (t >= off) ? ss[t - off] : 0;
    __syncthreads();
    ss[t] += a;
    __syncthreads();
  }
  int ex = ss[t] - v + bsumx[blockIdx.x];
  cursor[i] = ex;
  rowptr[i] = ex;
}

__global__ void k_scatter(const int* __restrict__ src, const int* __restrict__ dst,
                          const float* __restrict__ ea, int* __restrict__ cursor,
                          int* __restrict__ src_s, float* __restrict__ ea_s, int nE) {
  int e = blockIdx.x * blockDim.x + threadIdx.x;
  if (e >= nE) return;
  int d = dst[e];
  int pos = atomicAdd(&cursor[d], 1);
  src_s[pos] = src[e];
  ea_s[(size_t)pos * 3 + 0] = ea[(size_t)e * 3 + 0];
  ea_s[(size_t)pos * 3 + 1] = ea[(size_t)e * 3 + 1];
  ea_s[(size_t)pos * 3 + 2] = ea[(size_t)e * 3 + 2];
}

// ---------------- transpose weights to bf16 ----------------
__global__ void k_prep_w(const float* __restrict__ ew2, const float* __restrict__ cw1,
                         const float* __restrict__ cw2, unsigned short* __restrict__ wT) {
  int idx = blockIdx.x * blockDim.x + threadIdx.x;
  if (idx >= 7 * 16384) return;
  int m = idx >> 14, i = idx & 16383;
  int n = i >> 7, k = i & 127;
  const float* s = (m == 0) ? ew2 : (m <= 3 ? cw1 + (size_t)(m - 1) * 16384
                                            : cw2 + (size_t)(m - 4) * 16384);
  wT[idx] = f2bf(s[k * 128 + n]);
}

// ---------------- node encoder ----------------
__global__ void k_node_enc(const float* __restrict__ x, const float* __restrict__ w,
                           const float* __restrict__ b, unsigned short* __restrict__ h16, int nN) {
  int idx = blockIdx.x * blockDim.x + threadIdx.x;
  if (idx >= nN * HID) return;
  int i = idx >> 7, j = idx & 127;
  float acc = b[j];
  const float* xr = x + (size_t)i * 7;
#pragma unroll
  for (int k = 0; k < 7; ++k) acc += xr[k] * w[k * HID + j];
  h16[idx] = f2bf(acc);
}

// ---------------- one-time edge encoder GEMM -> e16 (direct C/D stores) ----------------
__global__ void __launch_bounds__(256) k_edge_gemm(
    const float* __restrict__ ea_s, const float* __restrict__ ew1, const float* __restrict__ eb1,
    const unsigned short* __restrict__ w2t, const float* __restrict__ eb2,
    unsigned short* __restrict__ e16, int nE) {
  __shared__ __attribute__((aligned(16))) unsigned short ts1[128 * LDP];
  __shared__ float eaL[384];
  int tid = threadIdx.x;
  int e0 = blockIdx.x * 128;                      // nE % 128 == 0
  for (int i = tid; i < 384; i += 256) eaL[i] = ea_s[(size_t)e0 * 3 + i];
  __syncthreads();
  {
    int j = tid & 127, r0 = (tid >> 7) * 64;
    float wa = ew1[j], wb = ew1[HID + j], wc = ew1[2 * HID + j], bj = eb1[j];
    for (int r = r0; r < r0 + 64; ++r) {
      float a = bj + eaL[r * 3] * wa + eaL[r * 3 + 1] * wb + eaL[r * 3 + 2] * wc;
      ts1[r * LDP + j] = f2bf(fmaxf(a, 0.f));
    }
  }
  __syncthreads();
  int wave = tid >> 6, lane = tid & 63;
  int l15 = lane & 15, quad = lane >> 4;
  int rbase = (wave >> 1) * 64, nbase = (wave & 1) * 64;
  f32x4 acc[4][4];
#pragma unroll
  for (int i = 0; i < 4; ++i)
#pragma unroll
    for (int j = 0; j < 4; ++j) acc[i][j] = (f32x4){0.f, 0.f, 0.f, 0.f};
  for (int kc = 0; kc < 4; ++kc) {
    int k0 = kc * 32 + quad * 8;
    s16x8 af[4], bf[4];
#pragma unroll
    for (int t = 0; t < 4; ++t)
      af[t] = *(const s16x8*)&ts1[(rbase + t * 16 + l15) * LDP + k0];
#pragma unroll
    for (int t = 0; t < 4; ++t)
      bf[t] = *(const s16x8*)&w2t[(size_t)(nbase + t * 16 + l15) * HID + k0];
#pragma unroll
    for (int i = 0; i < 4; ++i)
#pragma unroll
      for (int j = 0; j < 4; ++j)
        acc[i][j] = __builtin_amdgcn_mfma_f32_16x16x32_bf16(af[i], bf[j], acc[i][j], 0, 0, 0);
  }
  float ebv[4];
#pragma unroll
  for (int t = 0; t < 4; ++t) ebv[t] = eb2[nbase + t * 16 + l15];
#pragma unroll
  for (int tr = 0; tr < 4; ++tr)
#pragma unroll
    for (int reg = 0; reg < 4; ++reg) {
      int row = rbase + tr * 16 + quad * 4 + reg;   // C/D: col=lane&15, row=quad*4+reg
#pragma unroll
      for (int tc = 0; tc < 4; ++tc) {
        int col = nbase + tc * 16 + l15;
        e16[(size_t)(e0 + row) * HID + col] = f2bf(acc[tr][tc][reg] + ebv[tc]);
      }
    }
}

// ---------------- fused CSR-aggregate + conv MLP (no atomics; ping-pong h) ----------------
// phase A: wave w owns nodes [n0+32w, ...+32); all 64 lanes share node n (uniform
//   CSR bounds), lane owns cols (2*lane, 2*lane+1); fp32 register accumulation.
// h16in and h16out are DIFFERENT buffers (cross-block gather requires it).
__global__ void __launch_bounds__(256) k_conv_csr(
    const unsigned short* __restrict__ h16in, const unsigned short* __restrict__ e16,
    const int* __restrict__ src_s, const int* __restrict__ rowptr,
    const unsigned short* __restrict__ w1t, const float* __restrict__ b1,
    const unsigned short* __restrict__ w2t, const float* __restrict__ b2,
    unsigned short* __restrict__ h16out, int nN) {
  __shared__ __attribute__((aligned(16))) unsigned short zs[128 * LDP];
  int tid = threadIdx.x;
  int n0 = blockIdx.x * 128;
  int wave = tid >> 6, lane = tid & 63;
  // phase A
  {
    int c2 = lane * 2;
    for (int i = 0; i < 32; ++i) {
      int row = wave * 32 + i;
      int n = n0 + row;
      float z0 = 0.f, z1 = 0.f;
      if (n < nN) {
        float a0 = 0.f, a1 = 0.f;
        int rs = rowptr[n], re = rowptr[n + 1];
        for (int e = rs; e < re; ++e) {          // wave-uniform loop
          int s = src_s[e];                      // uniform -> scalar load
          unsigned int ev = *(const unsigned int*)&e16[(size_t)e * HID + c2];
          unsigned int hv = *(const unsigned int*)&h16in[(size_t)s * HID + c2];
          a0 += fmaxf(asf(hv << 16) + asf(ev << 16), 0.f);
          a1 += fmaxf(asf(hv & 0xffff0000u) + asf(ev & 0xffff0000u), 0.f);
        }
        unsigned int hn = *(const unsigned int*)&h16in[(size_t)n * HID + c2];
        z0 = asf(hn << 16) + a0;
        z1 = asf(hn & 0xffff0000u) + a1;
      }
      *(unsigned int*)&zs[row * LDP + c2] =
          (unsigned int)f2bf(z0) | ((unsigned int)f2bf(z1) << 16);
    }
  }
  __syncthreads();
  int l15 = lane & 15, quad = lane >> 4;
  int rbase = (wave >> 1) * 64, nbase = (wave & 1) * 64;
  f32x4 acc[4][4];
#pragma unroll
  for (int i = 0; i < 4; ++i)
#pragma unroll
    for (int j = 0; j < 4; ++j) acc[i][j] = (f32x4){0.f, 0.f, 0.f, 0.f};
  for (int kc = 0; kc < 4; ++kc) {
    int k0 = kc * 32 + quad * 8;
    s16x8 af[4], bf[4];
#pragma unroll
    for (int t = 0; t < 4; ++t)
      af[t] = *(const s16x8*)&zs[(rbase + t * 16 + l15) * LDP + k0];
#pragma unroll
    for (int t = 0; t < 4; ++t)
      bf[t] = *(const s16x8*)&w1t[(size_t)(nbase + t * 16 + l15) * HID + k0];
#pragma unroll
    for (int i = 0; i < 4; ++i)
#pragma unroll
      for (int j = 0; j < 4; ++j)
        acc[i][j] = __builtin_amdgcn_mfma_f32_16x16x32_bf16(af[i], bf[j], acc[i][j], 0, 0, 0);
  }
  __syncthreads();
  {
    float bv[4];
#pragma unroll
    for (int t = 0; t < 4; ++t) bv[t] = b1[nbase + t * 16 + l15];
#pragma unroll
    for (int tr = 0; tr < 4; ++tr)
#pragma unroll
      for (int tc = 0; tc < 4; ++tc)
#pragma unroll
        for (int reg = 0; reg < 4; ++reg) {
          int row = rbase + tr * 16 + quad * 4 + reg;
          int col = nbase + tc * 16 + l15;
          zs[row * LDP + col] = f2bf(fmaxf(acc[tr][tc][reg] + bv[tc], 0.f));
        }
  }
  __syncthreads();
#pragma unroll
  for (int i = 0; i < 4; ++i)
#pragma unroll
    for (int j = 0; j < 4; ++j) acc[i][j] = (f32x4){0.f, 0.f, 0.f, 0.f};
  for (int kc = 0; kc < 4; ++kc) {
    int k0 = kc * 32 + quad * 8;
    s16x8 af[4], bf[4];
#pragma unroll
    for (int t = 0; t < 4; ++t)
      af[t] = *(const s16x8*)&zs[(rbase + t * 16 + l15) * LDP + k0];
#pragma unroll
    for (int t = 0; t < 4; ++t)
      bf[t] = *(const s16x8*)&w2t[(size_t)(nbase + t * 16 + l15) * HID + k0];
#pragma unroll
    for (int i = 0; i < 4; ++i)
#pragma unroll
      for (int j = 0; j < 4; ++j)
        acc[i][j] = __builtin_amdgcn_mfma_f32_16x16x32_bf16(af[i], bf[j], acc[i][j], 0, 0, 0);
  }
  {
    float bv[4];
#pragma unroll
    for (int t = 0; t < 4; ++t) bv[t] = b2[nbase + t * 16 + l15];
#pragma unroll
    for (int tr = 0; tr < 4; ++tr)
#pragma unroll
      for (int reg = 0; reg < 4; ++reg) {
        int grow = n0 + rbase + tr * 16 + quad * 4 + reg;
        if (grow < nN) {
#pragma unroll
          for (int tc = 0; tc < 4; ++tc) {
            int col = nbase + tc * 16 + l15;
            h16out[(size_t)grow * HID + col] = f2bf(fmaxf(acc[tr][tc][reg] + bv[tc], 0.f));
          }
        }
      }
  }
}

// ---------------- counts ----------------
__global__ void k_counts(const int* __restrict__ batch, int* __restrict__ cnts, int nN) {
  int i = blockIdx.x * blockDim.x + threadIdx.x;
  if (i < nN) atomicAdd(&cnts[batch[i]], 1);
}

// ---------------- segment-reduced pool (batch sorted) ----------------
__global__ void __launch_bounds__(256) k_pool2(
    const unsigned short* __restrict__ h16, const int* __restrict__ batch,
    float* __restrict__ g, int nN) {
  __shared__ int bL[128];
  int tid = threadIdx.x;
  int n0 = blockIdx.x * 128;
  if (tid < 128) {
    int n = n0 + tid;
    bL[tid] = (n < nN) ? batch[n] : -1;
  }
  __syncthreads();
  int half = tid >> 7, col = tid & 127;
  int rs = half * 64;
  int cur = -1;
  float s = 0.f;
  for (int r = rs; r < rs + 64; ++r) {
    int b = bL[r];
    float v = (b >= 0) ? bf2f((unsigned int)h16[(size_t)(n0 + r) * HID + col]) : 0.f;
    if (b != cur) {
      if (cur >= 0) atomicAdd(&g[(size_t)cur * HID + col], s);
      cur = b; s = v;
    } else s += v;
  }
  if (cur >= 0) atomicAdd(&g[(size_t)cur * HID + col], s);
}

// ---------------- heads ----------------
__global__ void __launch_bounds__(128) k_head(
    const float* __restrict__ g, const int* __restrict__ counts,
    const float* __restrict__ clw1, const float* __restrict__ clb1,
    const float* __restrict__ clw2, const float* __restrict__ clb2,
    const float* __restrict__ rw1, const float* __restrict__ rb1,
    const float* __restrict__ rw2, const float* __restrict__ rb2,
    float* __restrict__ out, int nG) {
  __shared__ float gs[HID];
  int b = blockIdx.x;
  int tid = threadIdx.x;
  float cnt = fmaxf((float)counts[b], 1.f);
  gs[tid] = g[b * HID + tid] / cnt;
  __syncthreads();
  int wave = tid >> 6, lane = tid & 63;
  const float* w1 = wave ? rw1 : clw1;
  const float* b1 = wave ? rb1 : clb1;
  const float* w2 = wave ? rw2 : clw2;
  const float* b2 = wave ? rb2 : clb2;
  float acc = b1[lane];
  for (int k = 0; k < HID; ++k) acc += gs[k] * w1[k * 64 + lane];
  acc = fmaxf(acc, 0.f) * w2[lane];
#pragma unroll
  for (int off = 32; off; off >>= 1) acc += __shfl_down(acc, off);
  if (lane == 0) out[wave * nG + b] = acc + b2[0];
}

extern "C" void kernel_launch(void* const* d_in, const int* in_sizes, int n_in,
                              void* d_out, int out_size, void* d_ws, size_t ws_size,
                              hipStream_t stream) {
  const float* x      = (const float*)d_in[0];
  const float* ea     = (const float*)d_in[1];
  const int*   eidx   = (const int*)d_in[2];
  const int*   batch  = (const int*)d_in[3];
  const float* node_w = (const float*)d_in[4];
  const float* node_b = (const float*)d_in[5];
  const float* ew1    = (const float*)d_in[6];
  const float* eb1    = (const float*)d_in[7];
  const float* ew2    = (const float*)d_in[8];
  const float* eb2    = (const float*)d_in[9];
  const float* cw1    = (const float*)d_in[10];
  const float* cb1    = (const float*)d_in[11];
  const float* cw2    = (const float*)d_in[12];
  const float* cb2    = (const float*)d_in[13];
  const float* clw1   = (const float*)d_in[14];
  const float* clb1   = (const float*)d_in[15];
  const float* clw2   = (const float*)d_in[16];
  const float* clb2   = (const float*)d_in[17];
  const float* rw1    = (const float*)d_in[18];
  const float* rb1    = (const float*)d_in[19];
  const float* rw2    = (const float*)d_in[20];
  const float* rb2    = (const float*)d_in[21];
  float* out = (float*)d_out;

  int nN = in_sizes[3];        // 100000
  int nE = in_sizes[2] / 2;    // 640000 (divisible by 128)
  int nG = out_size / 2;       // 2048
  const int* src = eidx;
  const int* dst = eidx + nE;

  int NB = (nN + 255) / 256;
  int bins = NB * 256;

  // ---- workspace (~231 MB): g | cnts | wT | h16A | h16B | deg | cursor | rowptr | bsum | bsumx | src_s | ea_s | e16
  size_t hN = (size_t)nN * HID;
  size_t gN = (size_t)nG * HID;
  float* g    = (float*)d_ws;                       // gN
  int*   cnts = (int*)(g + gN);                     // nG
  unsigned short* wT   = (unsigned short*)(cnts + nG);  // 7*16384
  unsigned short* h16a = wT + 7 * 16384;            // hN
  unsigned short* h16b = h16a + hN;                 // hN
  int* deg    = (int*)(h16b + hN);                  // bins
  int* cursor = deg + bins;                         // bins
  int* rowptr = cursor + bins;                      // bins
  int* bsum   = rowptr + bins;                      // 512
  int* bsumx  = bsum + 512;                         // 512
  int* src_s  = bsumx + 512;                        // nE
  float* ea_s = (float*)(src_s + nE);               // 3*nE
  unsigned short* e16 = (unsigned short*)(ea_s + (size_t)3 * nE);  // nE*128

  // ---- counting sort of edges by dst (also builds CSR rowptr) ----
  k_zero4<<<(int)((bins / 4 + 255) / 256), 256, 0, stream>>>((float4*)deg, bins / 4);
  k_hist<<<(nE + 255) / 256, 256, 0, stream>>>(dst, deg, nE);
  k_scanA<<<NB, 256, 0, stream>>>(deg, bsum);
  k_scanB<<<1, 512, 0, stream>>>(bsum, bsumx, NB);
  k_scanC<<<NB, 256, 0, stream>>>(deg, bsumx, cursor, rowptr);
  k_scatter<<<(nE + 255) / 256, 256, 0, stream>>>(src, dst, ea, cursor, src_s, ea_s, nE);

  k_prep_w<<<(7 * 16384 + 255) / 256, 256, 0, stream>>>(ew2, cw1, cw2, wT);
  k_edge_gemm<<<nE / 128, 256, 0, stream>>>(ea_s, ew1, eb1, wT, eb2, e16, nE);
  k_node_enc<<<(nN * HID + 255) / 256, 256, 0, stream>>>(x, node_w, node_b, h16a, nN);

  // ping-pong: A->B, B->A, A->B  (final in h16b)
  unsigned short* hin  = h16a;
  unsigned short* hout = h16b;
  for (int l = 0; l < 3; ++l) {
    k_conv_csr<<<(nN + 127) / 128, 256, 0, stream>>>(
        hin, e16, src_s, rowptr,
        wT + (size_t)(1 + l) * 16384, cb1 + (size_t)l * HID,
        wT + (size_t)(4 + l) * 16384, cb2 + (size_t)l * HID, hout, nN);
    unsigned short* t = hin; hin = hout; hout = t;
  }
  // after 3 swaps, 'hin' points at the last-written buffer (h16b)

  k_zero4<<<(int)(((gN + nG) / 4 + 255) / 256), 256, 0, stream>>>((float4*)g, (gN + nG) / 4);
  k_counts<<<(nN + 255) / 256, 256, 0, stream>>>(batch, cnts, nN);
  k_pool2<<<(nN + 127) / 128, 256, 0, stream>>>(hin, batch, g, nN);
  k_head<<<nG, 128, 0, stream>>>(g, cnts, clw1, clb1, clw2, clb2,
                                 rw1, rb1, rw2, rb2, out, nG);
}

// Round 11
// 856.867 us; speedup vs baseline: 1.3679x; 1.3679x over previous
//
#include <hip/hip_runtime.h>

#define HID 128
#define LDP 136   // padded LDS row stride in bf16 elems (272 B)

typedef short s16x8 __attribute__((ext_vector_type(8)));
typedef float f32x4 __attribute__((ext_vector_type(4)));

__device__ __forceinline__ float bf2f(unsigned int u) {
  union { unsigned int i; float f; } v; v.i = u << 16; return v.f;
}
__device__ __forceinline__ float asf(unsigned int u) {
  union { unsigned int i; float f; } v; v.i = u; return v.f;
}
__device__ __forceinline__ unsigned short f2bf(float f) {
  union { float f; unsigned int i; } v; v.f = f;
  unsigned int r = v.i + 0x7fffu + ((v.i >> 16) & 1u);
  return (unsigned short)(r >> 16);
}

// ---------------- zero fill (vectorized) ----------------
__global__ void k_zero4(float4* __restrict__ p, size_t n4) {
  size_t i = (size_t)blockIdx.x * blockDim.x + threadIdx.x;
  if (i < n4) p[i] = (float4){0.f, 0.f, 0.f, 0.f};
}

// ---------------- counting sort ----------------
__global__ void k_hist(const int* __restrict__ dst, int* __restrict__ deg, int nE) {
  int e = blockIdx.x * blockDim.x + threadIdx.x;
  if (e < nE) atomicAdd(&deg[dst[e]], 1);
}

__global__ void k_scanA(const int* __restrict__ deg, int* __restrict__ bsum) {
  __shared__ int ss[256];
  int t = threadIdx.x;
  ss[t] = deg[blockIdx.x * 256 + t];
  __syncthreads();
  for (int off = 128; off; off >>= 1) {
    if (t < off) ss[t] += ss[t + off];
    __syncthreads();
  }
  if (t == 0) bsum[blockIdx.x] = ss[0];
}

__global__ void k_scanB(const int* __restrict__ bsum, int* __restrict__ bsumx, int NB) {
  __shared__ int sd[512];
  int t = threadIdx.x;
  int v = (t < NB) ? bsum[t] : 0;
  sd[t] = v;
  __syncthreads();
  for (int off = 1; off < 512; off <<= 1) {
    int a = (t >= off) ? sd[t - off] : 0;
    __syncthreads();
    sd[t] += a;
    __syncthreads();
  }
  if (t < NB) bsumx[t] = sd[t] - v;
}

// writes exclusive scan to BOTH cursor (mutated by scatter) and rowptr (kept)
__global__ void k_scanC(const int* __restrict__ deg, const int* __restrict__ bsumx,
                        int* __restrict__ cursor, int* __restrict__ rowptr) {
  __shared__ int ss[256];
  int t = threadIdx.x, i = blockIdx.x * 256 + t;
  int v = deg[i];
  ss[t] = v;
  __syncthreads();
  for (int off = 1; off < 256; off <<= 1) {
    int a = (t >= off) ? ss[t - off] : 0;
    __syncthreads();
    ss[t] += a;
    __syncthreads();
  }
  int ex = ss[t] - v + bsumx[blockIdx.x];
  cursor[i] = ex;
  rowptr[i] = ex;
}

__global__ void k_scatter(const int* __restrict__ src, const int* __restrict__ dst,
                          const float* __restrict__ ea, int* __restrict__ cursor,
                          int* __restrict__ src_s, int* __restrict__ dst_s,
                          float* __restrict__ ea_s, int nE) {
  int e = blockIdx.x * blockDim.x + threadIdx.x;
  if (e >= nE) return;
  int d = dst[e];
  int pos = atomicAdd(&cursor[d], 1);
  src_s[pos] = src[e];
  dst_s[pos] = d;
  ea_s[(size_t)pos * 3 + 0] = ea[(size_t)e * 3 + 0];
  ea_s[(size_t)pos * 3 + 1] = ea[(size_t)e * 3 + 1];
  ea_s[(size_t)pos * 3 + 2] = ea[(size_t)e * 3 + 2];
}

// ---------------- transpose weights to bf16 ----------------
__global__ void k_prep_w(const float* __restrict__ ew2, const float* __restrict__ cw1,
                         const float* __restrict__ cw2, unsigned short* __restrict__ wT) {
  int idx = blockIdx.x * blockDim.x + threadIdx.x;
  if (idx >= 7 * 16384) return;
  int m = idx >> 14, i = idx & 16383;
  int n = i >> 7, k = i & 127;
  const float* s = (m == 0) ? ew2 : (m <= 3 ? cw1 + (size_t)(m - 1) * 16384
                                            : cw2 + (size_t)(m - 4) * 16384);
  wT[idx] = f2bf(s[k * 128 + n]);
}

// ---------------- node encoder ----------------
__global__ void k_node_enc(const float* __restrict__ x, const float* __restrict__ w,
                           const float* __restrict__ b, unsigned short* __restrict__ h16, int nN) {
  int idx = blockIdx.x * blockDim.x + threadIdx.x;
  if (idx >= nN * HID) return;
  int i = idx >> 7, j = idx & 127;
  float acc = b[j];
  const float* xr = x + (size_t)i * 7;
#pragma unroll
  for (int k = 0; k < 7; ++k) acc += xr[k] * w[k * HID + j];
  h16[idx] = f2bf(acc);
}

// ---------------- one-time edge encoder GEMM -> e16 (direct C/D stores) ----------------
__global__ void __launch_bounds__(256) k_edge_gemm(
    const float* __restrict__ ea_s, const float* __restrict__ ew1, const float* __restrict__ eb1,
    const unsigned short* __restrict__ w2t, const float* __restrict__ eb2,
    unsigned short* __restrict__ e16, int nE) {
  __shared__ __attribute__((aligned(16))) unsigned short ts1[128 * LDP];
  __shared__ float eaL[384];
  int tid = threadIdx.x;
  int e0 = blockIdx.x * 128;                      // nE % 128 == 0
  for (int i = tid; i < 384; i += 256) eaL[i] = ea_s[(size_t)e0 * 3 + i];
  __syncthreads();
  {
    int j = tid & 127, r0 = (tid >> 7) * 64;
    float wa = ew1[j], wb = ew1[HID + j], wc = ew1[2 * HID + j], bj = eb1[j];
    for (int r = r0; r < r0 + 64; ++r) {
      float a = bj + eaL[r * 3] * wa + eaL[r * 3 + 1] * wb + eaL[r * 3 + 2] * wc;
      ts1[r * LDP + j] = f2bf(fmaxf(a, 0.f));
    }
  }
  __syncthreads();
  int wave = tid >> 6, lane = tid & 63;
  int l15 = lane & 15, quad = lane >> 4;
  int rbase = (wave >> 1) * 64, nbase = (wave & 1) * 64;
  f32x4 acc[4][4];
#pragma unroll
  for (int i = 0; i < 4; ++i)
#pragma unroll
    for (int j = 0; j < 4; ++j) acc[i][j] = (f32x4){0.f, 0.f, 0.f, 0.f};
  for (int kc = 0; kc < 4; ++kc) {
    int k0 = kc * 32 + quad * 8;
    s16x8 af[4], bf[4];
#pragma unroll
    for (int t = 0; t < 4; ++t)
      af[t] = *(const s16x8*)&ts1[(rbase + t * 16 + l15) * LDP + k0];
#pragma unroll
    for (int t = 0; t < 4; ++t)
      bf[t] = *(const s16x8*)&w2t[(size_t)(nbase + t * 16 + l15) * HID + k0];
#pragma unroll
    for (int i = 0; i < 4; ++i)
#pragma unroll
      for (int j = 0; j < 4; ++j)
        acc[i][j] = __builtin_amdgcn_mfma_f32_16x16x32_bf16(af[i], bf[j], acc[i][j], 0, 0, 0);
  }
  float ebv[4];
#pragma unroll
  for (int t = 0; t < 4; ++t) ebv[t] = eb2[nbase + t * 16 + l15];
#pragma unroll
  for (int tr = 0; tr < 4; ++tr)
#pragma unroll
    for (int reg = 0; reg < 4; ++reg) {
      int row = rbase + tr * 16 + quad * 4 + reg;   // C/D: col=lane&15, row=quad*4+reg
#pragma unroll
      for (int tc = 0; tc < 4; ++tc) {
        int col = nbase + tc * 16 + l15;
        e16[(size_t)(e0 + row) * HID + col] = f2bf(acc[tr][tc][reg] + ebv[tc]);
      }
    }
}

// ---------------- fused CSR-aggregate + conv MLP (no atomics; ping-pong h) ----------------
// phase A v2: wave owns 32 nodes = one CONTIGUOUS dst-sorted edge range.
//   Flat walk in chunks of 8: 8 independent (src,dst) scalar loads + 8 e16 +
//   8 gathered h16 b32 loads in flight, then uniform segment fold; one LDS
//   RMW flush per node. zs pre-initialized with h (covers degree-0 nodes).
__global__ void __launch_bounds__(256) k_conv_csr(
    const unsigned short* __restrict__ h16in, const unsigned short* __restrict__ e16,
    const int* __restrict__ src_s, const int* __restrict__ dst_s,
    const int* __restrict__ rowptr,
    const unsigned short* __restrict__ w1t, const float* __restrict__ b1,
    const unsigned short* __restrict__ w2t, const float* __restrict__ b2,
    unsigned short* __restrict__ h16out, int nN) {
  __shared__ __attribute__((aligned(16))) unsigned short zs[128 * LDP];
  int tid = threadIdx.x;
  int n0 = blockIdx.x * 128;
  int wave = tid >> 6, lane = tid & 63;
  // phase A
  {
    int c2 = lane * 2;
    int nodeBase = n0 + wave * 32;
    // init zs = h (bf16) for this wave's 32 rows
#pragma unroll
    for (int i = 0; i < 32; ++i) {
      int n = nodeBase + i;
      unsigned int hv = 0u;
      if (n < nN) hv = *(const unsigned int*)&h16in[(size_t)n * HID + c2];
      *(unsigned int*)&zs[(wave * 32 + i) * LDP + c2] = hv;
    }
    // contiguous edge range for these 32 nodes
    int nClamp = (nodeBase + 32 < nN) ? (nodeBase + 32) : nN;
    int eBeg = 0, eEnd = 0;
    if (nodeBase < nN) { eBeg = rowptr[nodeBase]; eEnd = rowptr[nClamp]; }
    float a0 = 0.f, a1 = 0.f;
    int cur = -1;
    for (int e = eBeg; e < eEnd; e += 8) {
      int cnt = eEnd - e; if (cnt > 8) cnt = 8;   // wave-uniform
      int sv[8], dv[8];
      unsigned int ev[8], hv[8];
#pragma unroll
      for (int i = 0; i < 8; ++i) if (i < cnt) { sv[i] = src_s[e + i]; dv[i] = dst_s[e + i]; }
#pragma unroll
      for (int i = 0; i < 8; ++i) if (i < cnt)
        ev[i] = *(const unsigned int*)&e16[(size_t)(e + i) * HID + c2];
#pragma unroll
      for (int i = 0; i < 8; ++i) if (i < cnt)
        hv[i] = *(const unsigned int*)&h16in[(size_t)sv[i] * HID + c2];
#pragma unroll
      for (int i = 0; i < 8; ++i) if (i < cnt) {
        if (dv[i] != cur) {                        // wave-uniform branch
          if (cur >= 0) {
            int row = cur - n0;
            unsigned int z = *(const unsigned int*)&zs[row * LDP + c2];
            float z0 = asf(z << 16) + a0, z1 = asf(z & 0xffff0000u) + a1;
            *(unsigned int*)&zs[row * LDP + c2] =
                (unsigned int)f2bf(z0) | ((unsigned int)f2bf(z1) << 16);
          }
          cur = dv[i]; a0 = 0.f; a1 = 0.f;
        }
        a0 += fmaxf(asf(hv[i] << 16) + asf(ev[i] << 16), 0.f);
        a1 += fmaxf(asf(hv[i] & 0xffff0000u) + asf(ev[i] & 0xffff0000u), 0.f);
      }
    }
    if (cur >= 0) {
      int row = cur - n0;
      unsigned int z = *(const unsigned int*)&zs[row * LDP + c2];
      float z0 = asf(z << 16) + a0, z1 = asf(z & 0xffff0000u) + a1;
      *(unsigned int*)&zs[row * LDP + c2] =
          (unsigned int)f2bf(z0) | ((unsigned int)f2bf(z1) << 16);
    }
  }
  __syncthreads();
  int l15 = lane & 15, quad = lane >> 4;
  int rbase = (wave >> 1) * 64, nbase = (wave & 1) * 64;
  f32x4 acc[4][4];
#pragma unroll
  for (int i = 0; i < 4; ++i)
#pragma unroll
    for (int j = 0; j < 4; ++j) acc[i][j] = (f32x4){0.f, 0.f, 0.f, 0.f};
  for (int kc = 0; kc < 4; ++kc) {
    int k0 = kc * 32 + quad * 8;
    s16x8 af[4], bf[4];
#pragma unroll
    for (int t = 0; t < 4; ++t)
      af[t] = *(const s16x8*)&zs[(rbase + t * 16 + l15) * LDP + k0];
#pragma unroll
    for (int t = 0; t < 4; ++t)
      bf[t] = *(const s16x8*)&w1t[(size_t)(nbase + t * 16 + l15) * HID + k0];
#pragma unroll
    for (int i = 0; i < 4; ++i)
#pragma unroll
      for (int j = 0; j < 4; ++j)
        acc[i][j] = __builtin_amdgcn_mfma_f32_16x16x32_bf16(af[i], bf[j], acc[i][j], 0, 0, 0);
  }
  __syncthreads();
  {
    float bv[4];
#pragma unroll
    for (int t = 0; t < 4; ++t) bv[t] = b1[nbase + t * 16 + l15];
#pragma unroll
    for (int tr = 0; tr < 4; ++tr)
#pragma unroll
      for (int tc = 0; tc < 4; ++tc)
#pragma unroll
        for (int reg = 0; reg < 4; ++reg) {
          int row = rbase + tr * 16 + quad * 4 + reg;
          int col = nbase + tc * 16 + l15;
          zs[row * LDP + col] = f2bf(fmaxf(acc[tr][tc][reg] + bv[tc], 0.f));
        }
  }
  __syncthreads();
#pragma unroll
  for (int i = 0; i < 4; ++i)
#pragma unroll
    for (int j = 0; j < 4; ++j) acc[i][j] = (f32x4){0.f, 0.f, 0.f, 0.f};
  for (int kc = 0; kc < 4; ++kc) {
    int k0 = kc * 32 + quad * 8;
    s16x8 af[4], bf[4];
#pragma unroll
    for (int t = 0; t < 4; ++t)
      af[t] = *(const s16x8*)&zs[(rbase + t * 16 + l15) * LDP + k0];
#pragma unroll
    for (int t = 0; t < 4; ++t)
      bf[t] = *(const s16x8*)&w2t[(size_t)(nbase + t * 16 + l15) * HID + k0];
#pragma unroll
    for (int i = 0; i < 4; ++i)
#pragma unroll
      for (int j = 0; j < 4; ++j)
        acc[i][j] = __builtin_amdgcn_mfma_f32_16x16x32_bf16(af[i], bf[j], acc[i][j], 0, 0, 0);
  }
  {
    float bv[4];
#pragma unroll
    for (int t = 0; t < 4; ++t) bv[t] = b2[nbase + t * 16 + l15];
#pragma unroll
    for (int tr = 0; tr < 4; ++tr)
#pragma unroll
      for (int reg = 0; reg < 4; ++reg) {
        int grow = n0 + rbase + tr * 16 + quad * 4 + reg;
        if (grow < nN) {
#pragma unroll
          for (int tc = 0; tc < 4; ++tc) {
            int col = nbase + tc * 16 + l15;
            h16out[(size_t)grow * HID + col] = f2bf(fmaxf(acc[tr][tc][reg] + bv[tc], 0.f));
          }
        }
      }
  }
}

// ---------------- counts ----------------
__global__ void k_counts(const int* __restrict__ batch, int* __restrict__ cnts, int nN) {
  int i = blockIdx.x * blockDim.x + threadIdx.x;
  if (i < nN) atomicAdd(&cnts[batch[i]], 1);
}

// ---------------- segment-reduced pool (batch sorted) ----------------
__global__ void __launch_bounds__(256) k_pool2(
    const unsigned short* __restrict__ h16, const int* __restrict__ batch,
    float* __restrict__ g, int nN) {
  __shared__ int bL[128];
  int tid = threadIdx.x;
  int n0 = blockIdx.x * 128;
  if (tid < 128) {
    int n = n0 + tid;
    bL[tid] = (n < nN) ? batch[n] : -1;
  }
  __syncthreads();
  int half = tid >> 7, col = tid & 127;
  int rs = half * 64;
  int cur = -1;
  float s = 0.f;
  for (int r = rs; r < rs + 64; ++r) {
    int b = bL[r];
    float v = (b >= 0) ? bf2f((unsigned int)h16[(size_t)(n0 + r) * HID + col]) : 0.f;
    if (b != cur) {
      if (cur >= 0) atomicAdd(&g[(size_t)cur * HID + col], s);
      cur = b; s = v;
    } else s += v;
  }
  if (cur >= 0) atomicAdd(&g[(size_t)cur * HID + col], s);
}

// ---------------- heads ----------------
__global__ void __launch_bounds__(128) k_head(
    const float* __restrict__ g, const int* __restrict__ counts,
    const float* __restrict__ clw1, const float* __restrict__ clb1,
    const float* __restrict__ clw2, const float* __restrict__ clb2,
    const float* __restrict__ rw1, const float* __restrict__ rb1,
    const float* __restrict__ rw2, const float* __restrict__ rb2,
    float* __restrict__ out, int nG) {
  __shared__ float gs[HID];
  int b = blockIdx.x;
  int tid = threadIdx.x;
  float cnt = fmaxf((float)counts[b], 1.f);
  gs[tid] = g[b * HID + tid] / cnt;
  __syncthreads();
  int wave = tid >> 6, lane = tid & 63;
  const float* w1 = wave ? rw1 : clw1;
  const float* b1 = wave ? rb1 : clb1;
  const float* w2 = wave ? rw2 : clw2;
  const float* b2 = wave ? rb2 : clb2;
  float acc = b1[lane];
  for (int k = 0; k < HID; ++k) acc += gs[k] * w1[k * 64 + lane];
  acc = fmaxf(acc, 0.f) * w2[lane];
#pragma unroll
  for (int off = 32; off; off >>= 1) acc += __shfl_down(acc, off);
  if (lane == 0) out[wave * nG + b] = acc + b2[0];
}

extern "C" void kernel_launch(void* const* d_in, const int* in_sizes, int n_in,
                              void* d_out, int out_size, void* d_ws, size_t ws_size,
                              hipStream_t stream) {
  const float* x      = (const float*)d_in[0];
  const float* ea     = (const float*)d_in[1];
  const int*   eidx   = (const int*)d_in[2];
  const int*   batch  = (const int*)d_in[3];
  const float* node_w = (const float*)d_in[4];
  const float* node_b = (const float*)d_in[5];
  const float* ew1    = (const float*)d_in[6];
  const float* eb1    = (const float*)d_in[7];
  const float* ew2    = (const float*)d_in[8];
  const float* eb2    = (const float*)d_in[9];
  const float* cw1    = (const float*)d_in[10];
  const float* cb1    = (const float*)d_in[11];
  const float* cw2    = (const float*)d_in[12];
  const float* cb2    = (const float*)d_in[13];
  const float* clw1   = (const float*)d_in[14];
  const float* clb1   = (const float*)d_in[15];
  const float* clw2   = (const float*)d_in[16];
  const float* clb2   = (const float*)d_in[17];
  const float* rw1    = (const float*)d_in[18];
  const float* rb1    = (const float*)d_in[19];
  const float* rw2    = (const float*)d_in[20];
  const float* rb2    = (const float*)d_in[21];
  float* out = (float*)d_out;

  int nN = in_sizes[3];        // 100000
  int nE = in_sizes[2] / 2;    // 640000 (divisible by 128)
  int nG = out_size / 2;       // 2048
  const int* src = eidx;
  const int* dst = eidx + nE;

  int NB = (nN + 255) / 256;
  int bins = NB * 256;

  // ---- workspace (~234 MB) ----
  size_t hN = (size_t)nN * HID;
  size_t gN = (size_t)nG * HID;
  float* g    = (float*)d_ws;                       // gN
  int*   cnts = (int*)(g + gN);                     // nG
  unsigned short* wT   = (unsigned short*)(cnts + nG);  // 7*16384
  unsigned short* h16a = wT + 7 * 16384;            // hN
  unsigned short* h16b = h16a + hN;                 // hN
  int* deg    = (int*)(h16b + hN);                  // bins
  int* cursor = deg + bins;                         // bins
  int* rowptr = cursor + bins;                      // bins
  int* bsum   = rowptr + bins;                      // 512
  int* bsumx  = bsum + 512;                         // 512
  int* src_s  = bsumx + 512;                        // nE
  int* dst_s  = src_s + nE;                         // nE
  float* ea_s = (float*)(dst_s + nE);               // 3*nE
  unsigned short* e16 = (unsigned short*)(ea_s + (size_t)3 * nE);  // nE*128

  // ---- counting sort of edges by dst (also builds CSR rowptr) ----
  k_zero4<<<(int)((bins / 4 + 255) / 256), 256, 0, stream>>>((float4*)deg, bins / 4);
  k_hist<<<(nE + 255) / 256, 256, 0, stream>>>(dst, deg, nE);
  k_scanA<<<NB, 256, 0, stream>>>(deg, bsum);
  k_scanB<<<1, 512, 0, stream>>>(bsum, bsumx, NB);
  k_scanC<<<NB, 256, 0, stream>>>(deg, bsumx, cursor, rowptr);
  k_scatter<<<(nE + 255) / 256, 256, 0, stream>>>(src, dst, ea, cursor,
                                                  src_s, dst_s, ea_s, nE);

  k_prep_w<<<(7 * 16384 + 255) / 256, 256, 0, stream>>>(ew2, cw1, cw2, wT);
  k_edge_gemm<<<nE / 128, 256, 0, stream>>>(ea_s, ew1, eb1, wT, eb2, e16, nE);
  k_node_enc<<<(nN * HID + 255) / 256, 256, 0, stream>>>(x, node_w, node_b, h16a, nN);

  // ping-pong: A->B, B->A, A->B  (final in h16b)
  unsigned short* hin  = h16a;
  unsigned short* hout = h16b;
  for (int l = 0; l < 3; ++l) {
    k_conv_csr<<<(nN + 127) / 128, 256, 0, stream>>>(
        hin, e16, src_s, dst_s, rowptr,
        wT + (size_t)(1 + l) * 16384, cb1 + (size_t)l * HID,
        wT + (size_t)(4 + l) * 16384, cb2 + (size_t)l * HID, hout, nN);
    unsigned short* t = hin; hin = hout; hout = t;
  }

  k_zero4<<<(int)(((gN + nG) / 4 + 255) / 256), 256, 0, stream>>>((float4*)g, (gN + nG) / 4);
  k_counts<<<(nN + 255) / 256, 256, 0, stream>>>(batch, cnts, nN);
  k_pool2<<<(nN + 127) / 128, 256, 0, stream>>>(hin, batch, g, nN);
  k_head<<<nG, 128, 0, stream>>>(g, cnts, clw1, clb1, clw2, clb2,
                                 rw1, rb1, rw2, rb2, out, nG);
}

// Round 12
// 714.213 us; speedup vs baseline: 1.6412x; 1.1997x over previous
//
#include <hip/hip_runtime.h>

#define HID 128
#define LDP 136   // padded LDS row stride in bf16 elems (272 B)

typedef short s16x8 __attribute__((ext_vector_type(8)));
typedef float f32x4 __attribute__((ext_vector_type(4)));

__device__ __forceinline__ float bf2f(unsigned int u) {
  union { unsigned int i; float f; } v; v.i = u << 16; return v.f;
}
__device__ __forceinline__ float asf(unsigned int u) {
  union { unsigned int i; float f; } v; v.i = u; return v.f;
}
__device__ __forceinline__ unsigned short f2bf(float f) {
  union { float f; unsigned int i; } v; v.f = f;
  unsigned int r = v.i + 0x7fffu + ((v.i >> 16) & 1u);
  return (unsigned short)(r >> 16);
}

// ---------------- zero fill (vectorized) ----------------
__global__ void k_zero4(float4* __restrict__ p, size_t n4) {
  size_t i = (size_t)blockIdx.x * blockDim.x + threadIdx.x;
  if (i < n4) p[i] = (float4){0.f, 0.f, 0.f, 0.f};
}

// ---------------- counting sort ----------------
__global__ void k_hist(const int* __restrict__ dst, int* __restrict__ deg, int nE) {
  int e = blockIdx.x * blockDim.x + threadIdx.x;
  if (e < nE) atomicAdd(&deg[dst[e]], 1);
}

__global__ void k_scanA(const int* __restrict__ deg, int* __restrict__ bsum) {
  __shared__ int ss[256];
  int t = threadIdx.x;
  ss[t] = deg[blockIdx.x * 256 + t];
  __syncthreads();
  for (int off = 128; off; off >>= 1) {
    if (t < off) ss[t] += ss[t + off];
    __syncthreads();
  }
  if (t == 0) bsum[blockIdx.x] = ss[0];
}

__global__ void k_scanB(const int* __restrict__ bsum, int* __restrict__ bsumx, int NB) {
  __shared__ int sd[512];
  int t = threadIdx.x;
  int v = (t < NB) ? bsum[t] : 0;
  sd[t] = v;
  __syncthreads();
  for (int off = 1; off < 512; off <<= 1) {
    int a = (t >= off) ? sd[t - off] : 0;
    __syncthreads();
    sd[t] += a;
    __syncthreads();
  }
  if (t < NB) bsumx[t] = sd[t] - v;
}

// writes exclusive scan to BOTH cursor (mutated by scatter) and rowptr (kept)
__global__ void k_scanC(const int* __restrict__ deg, const int* __restrict__ bsumx,
                        int* __restrict__ cursor, int* __restrict__ rowptr) {
  __shared__ int ss[256];
  int t = threadIdx.x, i = blockIdx.x * 256 + t;
  int v = deg[i];
  ss[t] = v;
  __syncthreads();
  for (int off = 1; off < 256; off <<= 1) {
    int a = (t >= off) ? ss[t - off] : 0;
    __syncthreads();
    ss[t] += a;
    __syncthreads();
  }
  int ex = ss[t] - v + bsumx[blockIdx.x];
  cursor[i] = ex;
  rowptr[i] = ex;
}

__global__ void k_scatter(const int* __restrict__ src, const int* __restrict__ dst,
                          const float* __restrict__ ea, int* __restrict__ cursor,
                          int* __restrict__ src_s, int* __restrict__ dst_s,
                          float* __restrict__ ea_s, int nE) {
  int e = blockIdx.x * blockDim.x + threadIdx.x;
  if (e >= nE) return;
  int d = dst[e];
  int pos = atomicAdd(&cursor[d], 1);
  src_s[pos] = src[e];
  dst_s[pos] = d;
  ea_s[(size_t)pos * 3 + 0] = ea[(size_t)e * 3 + 0];
  ea_s[(size_t)pos * 3 + 1] = ea[(size_t)e * 3 + 1];
  ea_s[(size_t)pos * 3 + 2] = ea[(size_t)e * 3 + 2];
}

// ---------------- transpose weights to bf16 ----------------
__global__ void k_prep_w(const float* __restrict__ ew2, const float* __restrict__ cw1,
                         const float* __restrict__ cw2, unsigned short* __restrict__ wT) {
  int idx = blockIdx.x * blockDim.x + threadIdx.x;
  if (idx >= 7 * 16384) return;
  int m = idx >> 14, i = idx & 16383;
  int n = i >> 7, k = i & 127;
  const float* s = (m == 0) ? ew2 : (m <= 3 ? cw1 + (size_t)(m - 1) * 16384
                                            : cw2 + (size_t)(m - 4) * 16384);
  wT[idx] = f2bf(s[k * 128 + n]);
}

// ---------------- node encoder ----------------
__global__ void k_node_enc(const float* __restrict__ x, const float* __restrict__ w,
                           const float* __restrict__ b, unsigned short* __restrict__ h16, int nN) {
  int idx = blockIdx.x * blockDim.x + threadIdx.x;
  if (idx >= nN * HID) return;
  int i = idx >> 7, j = idx & 127;
  float acc = b[j];
  const float* xr = x + (size_t)i * 7;
#pragma unroll
  for (int k = 0; k < 7; ++k) acc += xr[k] * w[k * HID + j];
  h16[idx] = f2bf(acc);
}

// ---------------- one-time edge encoder GEMM -> e16 (direct C/D stores) ----------------
__global__ void __launch_bounds__(256) k_edge_gemm(
    const float* __restrict__ ea_s, const float* __restrict__ ew1, const float* __restrict__ eb1,
    const unsigned short* __restrict__ w2t, const float* __restrict__ eb2,
    unsigned short* __restrict__ e16, int nE) {
  __shared__ __attribute__((aligned(16))) unsigned short ts1[128 * LDP];
  __shared__ float eaL[384];
  int tid = threadIdx.x;
  int e0 = blockIdx.x * 128;                      // nE % 128 == 0
  for (int i = tid; i < 384; i += 256) eaL[i] = ea_s[(size_t)e0 * 3 + i];
  __syncthreads();
  {
    int j = tid & 127, r0 = (tid >> 7) * 64;
    float wa = ew1[j], wb = ew1[HID + j], wc = ew1[2 * HID + j], bj = eb1[j];
    for (int r = r0; r < r0 + 64; ++r) {
      float a = bj + eaL[r * 3] * wa + eaL[r * 3 + 1] * wb + eaL[r * 3 + 2] * wc;
      ts1[r * LDP + j] = f2bf(fmaxf(a, 0.f));
    }
  }
  __syncthreads();
  int wave = tid >> 6, lane = tid & 63;
  int l15 = lane & 15, quad = lane >> 4;
  int rbase = (wave >> 1) * 64, nbase = (wave & 1) * 64;
  f32x4 acc[4][4];
#pragma unroll
  for (int i = 0; i < 4; ++i)
#pragma unroll
    for (int j = 0; j < 4; ++j) acc[i][j] = (f32x4){0.f, 0.f, 0.f, 0.f};
  for (int kc = 0; kc < 4; ++kc) {
    int k0 = kc * 32 + quad * 8;
    s16x8 af[4], bf[4];
#pragma unroll
    for (int t = 0; t < 4; ++t)
      af[t] = *(const s16x8*)&ts1[(rbase + t * 16 + l15) * LDP + k0];
#pragma unroll
    for (int t = 0; t < 4; ++t)
      bf[t] = *(const s16x8*)&w2t[(size_t)(nbase + t * 16 + l15) * HID + k0];
#pragma unroll
    for (int i = 0; i < 4; ++i)
#pragma unroll
      for (int j = 0; j < 4; ++j)
        acc[i][j] = __builtin_amdgcn_mfma_f32_16x16x32_bf16(af[i], bf[j], acc[i][j], 0, 0, 0);
  }
  float ebv[4];
#pragma unroll
  for (int t = 0; t < 4; ++t) ebv[t] = eb2[nbase + t * 16 + l15];
#pragma unroll
  for (int tr = 0; tr < 4; ++tr)
#pragma unroll
    for (int reg = 0; reg < 4; ++reg) {
      int row = rbase + tr * 16 + quad * 4 + reg;   // C/D: col=lane&15, row=quad*4+reg
#pragma unroll
      for (int tc = 0; tc < 4; ++tc) {
        int col = nbase + tc * 16 + l15;
        e16[(size_t)(e0 + row) * HID + col] = f2bf(acc[tr][tc][reg] + ebv[tc]);
      }
    }
}

// ---------------- fused CSR-aggregate + conv MLP, 64-node tile ----------------
// 4 waves; wave owns 16 nodes (one contiguous dst-sorted edge range, ~102 edges).
// phase A: chunk-8 flat walk, 16 indep loads in flight, uniform segment fold,
//          LDS RMW flush per node (zs pre-init = h covers degree-0).
// GEMM: M=64; wave = 32 rows x 64 cols (acc[2][4]).
__global__ void __launch_bounds__(256) k_conv_csr(
    const unsigned short* __restrict__ h16in, const unsigned short* __restrict__ e16,
    const int* __restrict__ src_s, const int* __restrict__ dst_s,
    const int* __restrict__ rowptr,
    const unsigned short* __restrict__ w1t, const float* __restrict__ b1,
    const unsigned short* __restrict__ w2t, const float* __restrict__ b2,
    unsigned short* __restrict__ h16out, int nN) {
  __shared__ __attribute__((aligned(16))) unsigned short zs[64 * LDP];
  int tid = threadIdx.x;
  int n0 = blockIdx.x * 64;
  int wave = tid >> 6, lane = tid & 63;
  // phase A
  {
    int c2 = lane * 2;
    int nodeBase = n0 + wave * 16;
#pragma unroll
    for (int i = 0; i < 16; ++i) {
      int n = nodeBase + i;
      unsigned int hv = 0u;
      if (n < nN) hv = *(const unsigned int*)&h16in[(size_t)n * HID + c2];
      *(unsigned int*)&zs[(wave * 16 + i) * LDP + c2] = hv;
    }
    int nClamp = (nodeBase + 16 < nN) ? (nodeBase + 16) : nN;
    int eBeg = 0, eEnd = 0;
    if (nodeBase < nN) { eBeg = rowptr[nodeBase]; eEnd = rowptr[nClamp]; }
    float a0 = 0.f, a1 = 0.f;
    int cur = -1;
    for (int e = eBeg; e < eEnd; e += 8) {
      int cnt = eEnd - e; if (cnt > 8) cnt = 8;   // wave-uniform
      int sv[8], dv[8];
      unsigned int ev[8], hv[8];
#pragma unroll
      for (int i = 0; i < 8; ++i) if (i < cnt) { sv[i] = src_s[e + i]; dv[i] = dst_s[e + i]; }
#pragma unroll
      for (int i = 0; i < 8; ++i) if (i < cnt)
        ev[i] = *(const unsigned int*)&e16[(size_t)(e + i) * HID + c2];
#pragma unroll
      for (int i = 0; i < 8; ++i) if (i < cnt)
        hv[i] = *(const unsigned int*)&h16in[(size_t)sv[i] * HID + c2];
#pragma unroll
      for (int i = 0; i < 8; ++i) if (i < cnt) {
        if (dv[i] != cur) {                        // wave-uniform branch
          if (cur >= 0) {
            int row = cur - n0;
            unsigned int z = *(const unsigned int*)&zs[row * LDP + c2];
            float z0 = asf(z << 16) + a0, z1 = asf(z & 0xffff0000u) + a1;
            *(unsigned int*)&zs[row * LDP + c2] =
                (unsigned int)f2bf(z0) | ((unsigned int)f2bf(z1) << 16);
          }
          cur = dv[i]; a0 = 0.f; a1 = 0.f;
        }
        a0 += fmaxf(asf(hv[i] << 16) + asf(ev[i] << 16), 0.f);
        a1 += fmaxf(asf(hv[i] & 0xffff0000u) + asf(ev[i] & 0xffff0000u), 0.f);
      }
    }
    if (cur >= 0) {
      int row = cur - n0;
      unsigned int z = *(const unsigned int*)&zs[row * LDP + c2];
      float z0 = asf(z << 16) + a0, z1 = asf(z & 0xffff0000u) + a1;
      *(unsigned int*)&zs[row * LDP + c2] =
          (unsigned int)f2bf(z0) | ((unsigned int)f2bf(z1) << 16);
    }
  }
  __syncthreads();
  int l15 = lane & 15, quad = lane >> 4;
  int rbase = (wave >> 1) * 32, nbase = (wave & 1) * 64;
  f32x4 acc[2][4];
#pragma unroll
  for (int i = 0; i < 2; ++i)
#pragma unroll
    for (int j = 0; j < 4; ++j) acc[i][j] = (f32x4){0.f, 0.f, 0.f, 0.f};
  for (int kc = 0; kc < 4; ++kc) {
    int k0 = kc * 32 + quad * 8;
    s16x8 af[2], bf[4];
#pragma unroll
    for (int t = 0; t < 2; ++t)
      af[t] = *(const s16x8*)&zs[(rbase + t * 16 + l15) * LDP + k0];
#pragma unroll
    for (int t = 0; t < 4; ++t)
      bf[t] = *(const s16x8*)&w1t[(size_t)(nbase + t * 16 + l15) * HID + k0];
#pragma unroll
    for (int i = 0; i < 2; ++i)
#pragma unroll
      for (int j = 0; j < 4; ++j)
        acc[i][j] = __builtin_amdgcn_mfma_f32_16x16x32_bf16(af[i], bf[j], acc[i][j], 0, 0, 0);
  }
  __syncthreads();
  {
    float bv[4];
#pragma unroll
    for (int t = 0; t < 4; ++t) bv[t] = b1[nbase + t * 16 + l15];
#pragma unroll
    for (int tr = 0; tr < 2; ++tr)
#pragma unroll
      for (int tc = 0; tc < 4; ++tc)
#pragma unroll
        for (int reg = 0; reg < 4; ++reg) {
          int row = rbase + tr * 16 + quad * 4 + reg;
          int col = nbase + tc * 16 + l15;
          zs[row * LDP + col] = f2bf(fmaxf(acc[tr][tc][reg] + bv[tc], 0.f));
        }
  }
  __syncthreads();
#pragma unroll
  for (int i = 0; i < 2; ++i)
#pragma unroll
    for (int j = 0; j < 4; ++j) acc[i][j] = (f32x4){0.f, 0.f, 0.f, 0.f};
  for (int kc = 0; kc < 4; ++kc) {
    int k0 = kc * 32 + quad * 8;
    s16x8 af[2], bf[4];
#pragma unroll
    for (int t = 0; t < 2; ++t)
      af[t] = *(const s16x8*)&zs[(rbase + t * 16 + l15) * LDP + k0];
#pragma unroll
    for (int t = 0; t < 4; ++t)
      bf[t] = *(const s16x8*)&w2t[(size_t)(nbase + t * 16 + l15) * HID + k0];
#pragma unroll
    for (int i = 0; i < 2; ++i)
#pragma unroll
      for (int j = 0; j < 4; ++j)
        acc[i][j] = __builtin_amdgcn_mfma_f32_16x16x32_bf16(af[i], bf[j], acc[i][j], 0, 0, 0);
  }
  {
    float bv[4];
#pragma unroll
    for (int t = 0; t < 4; ++t) bv[t] = b2[nbase + t * 16 + l15];
#pragma unroll
    for (int tr = 0; tr < 2; ++tr)
#pragma unroll
      for (int reg = 0; reg < 4; ++reg) {
        int grow = n0 + rbase + tr * 16 + quad * 4 + reg;
        if (grow < nN) {
#pragma unroll
          for (int tc = 0; tc < 4; ++tc) {
            int col = nbase + tc * 16 + l15;
            h16out[(size_t)grow * HID + col] = f2bf(fmaxf(acc[tr][tc][reg] + bv[tc], 0.f));
          }
        }
      }
  }
}

// ---------------- counts ----------------
__global__ void k_counts(const int* __restrict__ batch, int* __restrict__ cnts, int nN) {
  int i = blockIdx.x * blockDim.x + threadIdx.x;
  if (i < nN) atomicAdd(&cnts[batch[i]], 1);
}

// ---------------- segment-reduced pool (batch sorted) ----------------
__global__ void __launch_bounds__(256) k_pool2(
    const unsigned short* __restrict__ h16, const int* __restrict__ batch,
    float* __restrict__ g, int nN) {
  __shared__ int bL[128];
  int tid = threadIdx.x;
  int n0 = blockIdx.x * 128;
  if (tid < 128) {
    int n = n0 + tid;
    bL[tid] = (n < nN) ? batch[n] : -1;
  }
  __syncthreads();
  int half = tid >> 7, col = tid & 127;
  int rs = half * 64;
  int cur = -1;
  float s = 0.f;
  for (int r = rs; r < rs + 64; ++r) {
    int b = bL[r];
    float v = (b >= 0) ? bf2f((unsigned int)h16[(size_t)(n0 + r) * HID + col]) : 0.f;
    if (b != cur) {
      if (cur >= 0) atomicAdd(&g[(size_t)cur * HID + col], s);
      cur = b; s = v;
    } else s += v;
  }
  if (cur >= 0) atomicAdd(&g[(size_t)cur * HID + col], s);
}

// ---------------- heads ----------------
__global__ void __launch_bounds__(128) k_head(
    const float* __restrict__ g, const int* __restrict__ counts,
    const float* __restrict__ clw1, const float* __restrict__ clb1,
    const float* __restrict__ clw2, const float* __restrict__ clb2,
    const float* __restrict__ rw1, const float* __restrict__ rb1,
    const float* __restrict__ rw2, const float* __restrict__ rb2,
    float* __restrict__ out, int nG) {
  __shared__ float gs[HID];
  int b = blockIdx.x;
  int tid = threadIdx.x;
  float cnt = fmaxf((float)counts[b], 1.f);
  gs[tid] = g[b * HID + tid] / cnt;
  __syncthreads();
  int wave = tid >> 6, lane = tid & 63;
  const float* w1 = wave ? rw1 : clw1;
  const float* b1 = wave ? rb1 : clb1;
  const float* w2 = wave ? rw2 : clw2;
  const float* b2 = wave ? rb2 : clb2;
  float acc = b1[lane];
  for (int k = 0; k < HID; ++k) acc += gs[k] * w1[k * 64 + lane];
  acc = fmaxf(acc, 0.f) * w2[lane];
#pragma unroll
  for (int off = 32; off; off >>= 1) acc += __shfl_down(acc, off);
  if (lane == 0) out[wave * nG + b] = acc + b2[0];
}

extern "C" void kernel_launch(void* const* d_in, const int* in_sizes, int n_in,
                              void* d_out, int out_size, void* d_ws, size_t ws_size,
                              hipStream_t stream) {
  const float* x      = (const float*)d_in[0];
  const float* ea     = (const float*)d_in[1];
  const int*   eidx   = (const int*)d_in[2];
  const int*   batch  = (const int*)d_in[3];
  const float* node_w = (const float*)d_in[4];
  const float* node_b = (const float*)d_in[5];
  const float* ew1    = (const float*)d_in[6];
  const float* eb1    = (const float*)d_in[7];
  const float* ew2    = (const float*)d_in[8];
  const float* eb2    = (const float*)d_in[9];
  const float* cw1    = (const float*)d_in[10];
  const float* cb1    = (const float*)d_in[11];
  const float* cw2    = (const float*)d_in[12];
  const float* cb2    = (const float*)d_in[13];
  const float* clw1   = (const float*)d_in[14];
  const float* clb1   = (const float*)d_in[15];
  const float* clw2   = (const float*)d_in[16];
  const float* clb2   = (const float*)d_in[17];
  const float* rw1    = (const float*)d_in[18];
  const float* rb1    = (const float*)d_in[19];
  const float* rw2    = (const float*)d_in[20];
  const float* rb2    = (const float*)d_in[21];
  float* out = (float*)d_out;

  int nN = in_sizes[3];        // 100000
  int nE = in_sizes[2] / 2;    // 640000 (divisible by 128)
  int nG = out_size / 2;       // 2048
  const int* src = eidx;
  const int* dst = eidx + nE;

  int NB = (nN + 255) / 256;
  int bins = NB * 256;

  // ---- workspace (~234 MB) ----
  size_t hN = (size_t)nN * HID;
  size_t gN = (size_t)nG * HID;
  float* g    = (float*)d_ws;                       // gN
  int*   cnts = (int*)(g + gN);                     // nG
  unsigned short* wT   = (unsigned short*)(cnts + nG);  // 7*16384
  unsigned short* h16a = wT + 7 * 16384;            // hN
  unsigned short* h16b = h16a + hN;                 // hN
  int* deg    = (int*)(h16b + hN);                  // bins
  int* cursor = deg + bins;                         // bins
  int* rowptr = cursor + bins;                      // bins
  int* bsum   = rowptr + bins;                      // 512
  int* bsumx  = bsum + 512;                         // 512
  int* src_s  = bsumx + 512;                        // nE
  int* dst_s  = src_s + nE;                         // nE
  float* ea_s = (float*)(dst_s + nE);               // 3*nE
  unsigned short* e16 = (unsigned short*)(ea_s + (size_t)3 * nE);  // nE*128

  // ---- counting sort of edges by dst (also builds CSR rowptr) ----
  k_zero4<<<(int)((bins / 4 + 255) / 256), 256, 0, stream>>>((float4*)deg, bins / 4);
  k_hist<<<(nE + 255) / 256, 256, 0, stream>>>(dst, deg, nE);
  k_scanA<<<NB, 256, 0, stream>>>(deg, bsum);
  k_scanB<<<1, 512, 0, stream>>>(bsum, bsumx, NB);
  k_scanC<<<NB, 256, 0, stream>>>(deg, bsumx, cursor, rowptr);
  k_scatter<<<(nE + 255) / 256, 256, 0, stream>>>(src, dst, ea, cursor,
                                                  src_s, dst_s, ea_s, nE);

  k_prep_w<<<(7 * 16384 + 255) / 256, 256, 0, stream>>>(ew2, cw1, cw2, wT);
  k_edge_gemm<<<nE / 128, 256, 0, stream>>>(ea_s, ew1, eb1, wT, eb2, e16, nE);
  k_node_enc<<<(nN * HID + 255) / 256, 256, 0, stream>>>(x, node_w, node_b, h16a, nN);

  // ping-pong: A->B, B->A, A->B  (final in h16b)
  unsigned short* hin  = h16a;
  unsigned short* hout = h16b;
  for (int l = 0; l < 3; ++l) {
    k_conv_csr<<<(nN + 63) / 64, 256, 0, stream>>>(
        hin, e16, src_s, dst_s, rowptr,
        wT + (size_t)(1 + l) * 16384, cb1 + (size_t)l * HID,
        wT + (size_t)(4 + l) * 16384, cb2 + (size_t)l * HID, hout, nN);
    unsigned short* t = hin; hin = hout; hout = t;
  }

  k_zero4<<<(int)(((gN + nG) / 4 + 255) / 256), 256, 0, stream>>>((float4*)g, (gN + nG) / 4);
  k_counts<<<(nN + 255) / 256, 256, 0, stream>>>(batch, cnts, nN);
  k_pool2<<<(nN + 127) / 128, 256, 0, stream>>>(hin, batch, g, nN);
  k_head<<<nG, 128, 0, stream>>>(g, cnts, clw1, clb1, clw2, clb2,
                                 rw1, rb1, rw2, rb2, out, nG);
}

// Round 13
// 665.577 us; speedup vs baseline: 1.7611x; 1.0731x over previous
//
#include <hip/hip_runtime.h>

#define HID 128
#define LDP 136   // padded LDS row stride in bf16 elems (272 B)

typedef short s16x8 __attribute__((ext_vector_type(8)));
typedef float f32x4 __attribute__((ext_vector_type(4)));

__device__ __forceinline__ float bf2f(unsigned int u) {
  union { unsigned int i; float f; } v; v.i = u << 16; return v.f;
}
__device__ __forceinline__ float asf(unsigned int u) {
  union { unsigned int i; float f; } v; v.i = u; return v.f;
}
__device__ __forceinline__ unsigned short f2bf(float f) {
  union { float f; unsigned int i; } v; v.f = f;
  unsigned int r = v.i + 0x7fffu + ((v.i >> 16) & 1u);
  return (unsigned short)(r >> 16);
}

// ---------------- zero fill (vectorized) ----------------
__global__ void k_zero4(float4* __restrict__ p, size_t n4) {
  size_t i = (size_t)blockIdx.x * blockDim.x + threadIdx.x;
  if (i < n4) p[i] = (float4){0.f, 0.f, 0.f, 0.f};
}

// ---------------- counting sort ----------------
__global__ void k_hist(const int* __restrict__ dst, int* __restrict__ deg, int nE) {
  int e = blockIdx.x * blockDim.x + threadIdx.x;
  if (e < nE) atomicAdd(&deg[dst[e]], 1);
}

__global__ void k_scanA(const int* __restrict__ deg, int* __restrict__ bsum) {
  __shared__ int ss[256];
  int t = threadIdx.x;
  ss[t] = deg[blockIdx.x * 256 + t];
  __syncthreads();
  for (int off = 128; off; off >>= 1) {
    if (t < off) ss[t] += ss[t + off];
    __syncthreads();
  }
  if (t == 0) bsum[blockIdx.x] = ss[0];
}

__global__ void k_scanB(const int* __restrict__ bsum, int* __restrict__ bsumx, int NB) {
  __shared__ int sd[512];
  int t = threadIdx.x;
  int v = (t < NB) ? bsum[t] : 0;
  sd[t] = v;
  __syncthreads();
  for (int off = 1; off < 512; off <<= 1) {
    int a = (t >= off) ? sd[t - off] : 0;
    __syncthreads();
    sd[t] += a;
    __syncthreads();
  }
  if (t < NB) bsumx[t] = sd[t] - v;
}

// writes exclusive scan to BOTH cursor (mutated by scatter) and rowptr (kept)
__global__ void k_scanC(const int* __restrict__ deg, const int* __restrict__ bsumx,
                        int* __restrict__ cursor, int* __restrict__ rowptr) {
  __shared__ int ss[256];
  int t = threadIdx.x, i = blockIdx.x * 256 + t;
  int v = deg[i];
  ss[t] = v;
  __syncthreads();
  for (int off = 1; off < 256; off <<= 1) {
    int a = (t >= off) ? ss[t - off] : 0;
    __syncthreads();
    ss[t] += a;
    __syncthreads();
  }
  int ex = ss[t] - v + bsumx[blockIdx.x];
  cursor[i] = ex;
  rowptr[i] = ex;
}

__global__ void k_scatter(const int* __restrict__ src, const int* __restrict__ dst,
                          const float* __restrict__ ea, int* __restrict__ cursor,
                          int* __restrict__ src_s, float* __restrict__ ea_s, int nE) {
  int e = blockIdx.x * blockDim.x + threadIdx.x;
  if (e >= nE) return;
  int d = dst[e];
  int pos = atomicAdd(&cursor[d], 1);
  src_s[pos] = src[e];
  ea_s[(size_t)pos * 3 + 0] = ea[(size_t)e * 3 + 0];
  ea_s[(size_t)pos * 3 + 1] = ea[(size_t)e * 3 + 1];
  ea_s[(size_t)pos * 3 + 2] = ea[(size_t)e * 3 + 2];
}

// ---------------- transpose weights to bf16 ----------------
__global__ void k_prep_w(const float* __restrict__ ew2, const float* __restrict__ cw1,
                         const float* __restrict__ cw2, unsigned short* __restrict__ wT) {
  int idx = blockIdx.x * blockDim.x + threadIdx.x;
  if (idx >= 7 * 16384) return;
  int m = idx >> 14, i = idx & 16383;
  int n = i >> 7, k = i & 127;
  const float* s = (m == 0) ? ew2 : (m <= 3 ? cw1 + (size_t)(m - 1) * 16384
                                            : cw2 + (size_t)(m - 4) * 16384);
  wT[idx] = f2bf(s[k * 128 + n]);
}

// ---------------- node encoder ----------------
__global__ void k_node_enc(const float* __restrict__ x, const float* __restrict__ w,
                           const float* __restrict__ b, unsigned short* __restrict__ h16, int nN) {
  int idx = blockIdx.x * blockDim.x + threadIdx.x;
  if (idx >= nN * HID) return;
  int i = idx >> 7, j = idx & 127;
  float acc = b[j];
  const float* xr = x + (size_t)i * 7;
#pragma unroll
  for (int k = 0; k < 7; ++k) acc += xr[k] * w[k * HID + j];
  h16[idx] = f2bf(acc);
}

// ---------------- one-time edge encoder GEMM -> e16 (direct C/D stores) ----------------
__global__ void __launch_bounds__(256) k_edge_gemm(
    const float* __restrict__ ea_s, const float* __restrict__ ew1, const float* __restrict__ eb1,
    const unsigned short* __restrict__ w2t, const float* __restrict__ eb2,
    unsigned short* __restrict__ e16, int nE) {
  __shared__ __attribute__((aligned(16))) unsigned short ts1[128 * LDP];
  __shared__ float eaL[384];
  int tid = threadIdx.x;
  int e0 = blockIdx.x * 128;                      // nE % 128 == 0
  for (int i = tid; i < 384; i += 256) eaL[i] = ea_s[(size_t)e0 * 3 + i];
  __syncthreads();
  {
    int j = tid & 127, r0 = (tid >> 7) * 64;
    float wa = ew1[j], wb = ew1[HID + j], wc = ew1[2 * HID + j], bj = eb1[j];
    for (int r = r0; r < r0 + 64; ++r) {
      float a = bj + eaL[r * 3] * wa + eaL[r * 3 + 1] * wb + eaL[r * 3 + 2] * wc;
      ts1[r * LDP + j] = f2bf(fmaxf(a, 0.f));
    }
  }
  __syncthreads();
  int wave = tid >> 6, lane = tid & 63;
  int l15 = lane & 15, quad = lane >> 4;
  int rbase = (wave >> 1) * 64, nbase = (wave & 1) * 64;
  f32x4 acc[4][4];
#pragma unroll
  for (int i = 0; i < 4; ++i)
#pragma unroll
    for (int j = 0; j < 4; ++j) acc[i][j] = (f32x4){0.f, 0.f, 0.f, 0.f};
  for (int kc = 0; kc < 4; ++kc) {
    int k0 = kc * 32 + quad * 8;
    s16x8 af[4], bf[4];
#pragma unroll
    for (int t = 0; t < 4; ++t)
      af[t] = *(const s16x8*)&ts1[(rbase + t * 16 + l15) * LDP + k0];
#pragma unroll
    for (int t = 0; t < 4; ++t)
      bf[t] = *(const s16x8*)&w2t[(size_t)(nbase + t * 16 + l15) * HID + k0];
#pragma unroll
    for (int i = 0; i < 4; ++i)
#pragma unroll
      for (int j = 0; j < 4; ++j)
        acc[i][j] = __builtin_amdgcn_mfma_f32_16x16x32_bf16(af[i], bf[j], acc[i][j], 0, 0, 0);
  }
  float ebv[4];
#pragma unroll
  for (int t = 0; t < 4; ++t) ebv[t] = eb2[nbase + t * 16 + l15];
#pragma unroll
  for (int tr = 0; tr < 4; ++tr)
#pragma unroll
    for (int reg = 0; reg < 4; ++reg) {
      int row = rbase + tr * 16 + quad * 4 + reg;   // C/D: col=lane&15, row=quad*4+reg
#pragma unroll
      for (int tc = 0; tc < 4; ++tc) {
        int col = nbase + tc * 16 + l15;
        e16[(size_t)(e0 + row) * HID + col] = f2bf(acc[tr][tc][reg] + ebv[tc]);
      }
    }
}

// ---------------- fused CSR-aggregate + conv MLP, 64-node tile, pipelined ----------------
// phase A: wave owns 16 nodes (contiguous dst-sorted edge range). Node boundaries
//   from rowptr (cached in LDS) -> no dst loads. Software pipeline depth 2:
//   while folding chunk k, chunk k+1's e16/h16 loads and chunk k+2's src loads
//   are in flight. LDS RMW flush per node; zs pre-init = h covers degree-0.
__global__ void __launch_bounds__(256) k_conv_csr(
    const unsigned short* __restrict__ h16in, const unsigned short* __restrict__ e16,
    const int* __restrict__ src_s, const int* __restrict__ rowptr,
    const unsigned short* __restrict__ w1t, const float* __restrict__ b1,
    const unsigned short* __restrict__ w2t, const float* __restrict__ b2,
    unsigned short* __restrict__ h16out, int nN) {
  __shared__ __attribute__((aligned(16))) unsigned short zs[64 * LDP];
  __shared__ int rpS[4][20];
  int tid = threadIdx.x;
  int n0 = blockIdx.x * 64;
  int wave = tid >> 6, lane = tid & 63;
  // phase A
  {
    int c2 = lane * 2;
    int wbase = wave * 16;
    int nodeBase = n0 + wbase;
    int nCnt = nN - nodeBase; if (nCnt > 16) nCnt = 16; if (nCnt < 0) nCnt = 0;
    // init zs = h (bf16) for this wave's 16 rows
#pragma unroll
    for (int i = 0; i < 16; ++i) {
      int n = nodeBase + i;
      unsigned int hv = 0u;
      if (n < nN) hv = *(const unsigned int*)&h16in[(size_t)n * HID + c2];
      *(unsigned int*)&zs[(wbase + i) * LDP + c2] = hv;
    }
    // cache rowptr[nodeBase .. nodeBase+16] (clamped) in LDS
    if (lane < 17) {
      int i = (lane < nCnt) ? lane : nCnt;
      rpS[wave][lane] = (nCnt > 0) ? rowptr[nodeBase + i] : 0;
    }
    int eBeg = rpS[wave][0];
    int eEnd = rpS[wave][16];
    if (nCnt > 0 && eBeg < eEnd) {
      float a0 = 0.f, a1 = 0.f;
      int ni = 0;
      int rpEnd = rpS[wave][1];
      int sv0[8], sv1[8];
      unsigned int ev0[8], hv0[8], ev1[8], hv1[8];

#define LOAD_S(svv, base)                                            \
  _Pragma("unroll")                                                  \
  for (int i = 0; i < 8; ++i) {                                      \
    int ix = (base) + i; if (ix >= eEnd) ix = eEnd - 1;              \
    svv[i] = src_s[ix];                                              \
  }
#define LOAD_EH(evv, hvv, svv, base)                                 \
  _Pragma("unroll")                                                  \
  for (int i = 0; i < 8; ++i) {                                      \
    int ix = (base) + i; if (ix >= eEnd) ix = eEnd - 1;              \
    evv[i] = *(const unsigned int*)&e16[(size_t)ix * HID + c2];      \
    hvv[i] = *(const unsigned int*)&h16in[(size_t)svv[i] * HID + c2];\
  }
#define FLUSH()                                                      \
  { int row = wbase + ni;                                            \
    unsigned int z = *(const unsigned int*)&zs[row * LDP + c2];      \
    float z0 = asf(z << 16) + a0, z1 = asf(z & 0xffff0000u) + a1;    \
    *(unsigned int*)&zs[row * LDP + c2] =                            \
        (unsigned int)f2bf(z0) | ((unsigned int)f2bf(z1) << 16);     \
    a0 = 0.f; a1 = 0.f; }
#define FOLD(evv, hvv, base)                                         \
  { int cnt = eEnd - (base); if (cnt > 8) cnt = 8;                   \
    _Pragma("unroll")                                                \
    for (int i = 0; i < 8; ++i) if (i < cnt) {                       \
      int eg = (base) + i;                                           \
      while (eg >= rpEnd) { FLUSH(); ++ni; rpEnd = rpS[wave][ni + 1]; } \
      a0 += fmaxf(asf(hvv[i] << 16) + asf(evv[i] << 16), 0.f);       \
      a1 += fmaxf(asf(hvv[i] & 0xffff0000u) + asf(evv[i] & 0xffff0000u), 0.f); \
    } }

      LOAD_S(sv0, eBeg)
      LOAD_S(sv1, eBeg + 8)
      LOAD_EH(ev0, hv0, sv0, eBeg)
      for (int e = eBeg; e < eEnd; e += 16) {
        // chunk @ e (buffers 0); sv1 holds e+8
        if (e + 16 < eEnd) LOAD_S(sv0, e + 16)          // sv0 consumed, reuse for e+16
        if (e + 8 < eEnd)  LOAD_EH(ev1, hv1, sv1, e + 8)
        FOLD(ev0, hv0, e)
        // chunk @ e+8 (buffers 1); sv0 holds e+16
        if (e + 8 < eEnd) {
          if (e + 24 < eEnd) LOAD_S(sv1, e + 24)
          if (e + 16 < eEnd) LOAD_EH(ev0, hv0, sv0, e + 16)
          FOLD(ev1, hv1, e + 8)
        }
      }
      FLUSH()
#undef LOAD_S
#undef LOAD_EH
#undef FLUSH
#undef FOLD
    }
  }
  __syncthreads();
  int l15 = lane & 15, quad = lane >> 4;
  int rbase = (wave >> 1) * 32, nbase = (wave & 1) * 64;
  f32x4 acc[2][4];
#pragma unroll
  for (int i = 0; i < 2; ++i)
#pragma unroll
    for (int j = 0; j < 4; ++j) acc[i][j] = (f32x4){0.f, 0.f, 0.f, 0.f};
  for (int kc = 0; kc < 4; ++kc) {
    int k0 = kc * 32 + quad * 8;
    s16x8 af[2], bf[4];
#pragma unroll
    for (int t = 0; t < 2; ++t)
      af[t] = *(const s16x8*)&zs[(rbase + t * 16 + l15) * LDP + k0];
#pragma unroll
    for (int t = 0; t < 4; ++t)
      bf[t] = *(const s16x8*)&w1t[(size_t)(nbase + t * 16 + l15) * HID + k0];
#pragma unroll
    for (int i = 0; i < 2; ++i)
#pragma unroll
      for (int j = 0; j < 4; ++j)
        acc[i][j] = __builtin_amdgcn_mfma_f32_16x16x32_bf16(af[i], bf[j], acc[i][j], 0, 0, 0);
  }
  __syncthreads();
  {
    float bv[4];
#pragma unroll
    for (int t = 0; t < 4; ++t) bv[t] = b1[nbase + t * 16 + l15];
#pragma unroll
    for (int tr = 0; tr < 2; ++tr)
#pragma unroll
      for (int tc = 0; tc < 4; ++tc)
#pragma unroll
        for (int reg = 0; reg < 4; ++reg) {
          int row = rbase + tr * 16 + quad * 4 + reg;
          int col = nbase + tc * 16 + l15;
          zs[row * LDP + col] = f2bf(fmaxf(acc[tr][tc][reg] + bv[tc], 0.f));
        }
  }
  __syncthreads();
#pragma unroll
  for (int i = 0; i < 2; ++i)
#pragma unroll
    for (int j = 0; j < 4; ++j) acc[i][j] = (f32x4){0.f, 0.f, 0.f, 0.f};
  for (int kc = 0; kc < 4; ++kc) {
    int k0 = kc * 32 + quad * 8;
    s16x8 af[2], bf[4];
#pragma unroll
    for (int t = 0; t < 2; ++t)
      af[t] = *(const s16x8*)&zs[(rbase + t * 16 + l15) * LDP + k0];
#pragma unroll
    for (int t = 0; t < 4; ++t)
      bf[t] = *(const s16x8*)&w2t[(size_t)(nbase + t * 16 + l15) * HID + k0];
#pragma unroll
    for (int i = 0; i < 2; ++i)
#pragma unroll
      for (int j = 0; j < 4; ++j)
        acc[i][j] = __builtin_amdgcn_mfma_f32_16x16x32_bf16(af[i], bf[j], acc[i][j], 0, 0, 0);
  }
  {
    float bv[4];
#pragma unroll
    for (int t = 0; t < 4; ++t) bv[t] = b2[nbase + t * 16 + l15];
#pragma unroll
    for (int tr = 0; tr < 2; ++tr)
#pragma unroll
      for (int reg = 0; reg < 4; ++reg) {
        int grow = n0 + rbase + tr * 16 + quad * 4 + reg;
        if (grow < nN) {
#pragma unroll
          for (int tc = 0; tc < 4; ++tc) {
            int col = nbase + tc * 16 + l15;
            h16out[(size_t)grow * HID + col] = f2bf(fmaxf(acc[tr][tc][reg] + bv[tc], 0.f));
          }
        }
      }
  }
}

// ---------------- counts ----------------
__global__ void k_counts(const int* __restrict__ batch, int* __restrict__ cnts, int nN) {
  int i = blockIdx.x * blockDim.x + threadIdx.x;
  if (i < nN) atomicAdd(&cnts[batch[i]], 1);
}

// ---------------- segment-reduced pool (batch sorted) ----------------
__global__ void __launch_bounds__(256) k_pool2(
    const unsigned short* __restrict__ h16, const int* __restrict__ batch,
    float* __restrict__ g, int nN) {
  __shared__ int bL[128];
  int tid = threadIdx.x;
  int n0 = blockIdx.x * 128;
  if (tid < 128) {
    int n = n0 + tid;
    bL[tid] = (n < nN) ? batch[n] : -1;
  }
  __syncthreads();
  int half = tid >> 7, col = tid & 127;
  int rs = half * 64;
  int cur = -1;
  float s = 0.f;
  for (int r = rs; r < rs + 64; ++r) {
    int b = bL[r];
    float v = (b >= 0) ? bf2f((unsigned int)h16[(size_t)(n0 + r) * HID + col]) : 0.f;
    if (b != cur) {
      if (cur >= 0) atomicAdd(&g[(size_t)cur * HID + col], s);
      cur = b; s = v;
    } else s += v;
  }
  if (cur >= 0) atomicAdd(&g[(size_t)cur * HID + col], s);
}

// ---------------- heads ----------------
__global__ void __launch_bounds__(128) k_head(
    const float* __restrict__ g, const int* __restrict__ counts,
    const float* __restrict__ clw1, const float* __restrict__ clb1,
    const float* __restrict__ clw2, const float* __restrict__ clb2,
    const float* __restrict__ rw1, const float* __restrict__ rb1,
    const float* __restrict__ rw2, const float* __restrict__ rb2,
    float* __restrict__ out, int nG) {
  __shared__ float gs[HID];
  int b = blockIdx.x;
  int tid = threadIdx.x;
  float cnt = fmaxf((float)counts[b], 1.f);
  gs[tid] = g[b * HID + tid] / cnt;
  __syncthreads();
  int wave = tid >> 6, lane = tid & 63;
  const float* w1 = wave ? rw1 : clw1;
  const float* b1 = wave ? rb1 : clb1;
  const float* w2 = wave ? rw2 : clw2;
  const float* b2 = wave ? rb2 : clb2;
  float acc = b1[lane];
  for (int k = 0; k < HID; ++k) acc += gs[k] * w1[k * 64 + lane];
  acc = fmaxf(acc, 0.f) * w2[lane];
#pragma unroll
  for (int off = 32; off; off >>= 1) acc += __shfl_down(acc, off);
  if (lane == 0) out[wave * nG + b] = acc + b2[0];
}

extern "C" void kernel_launch(void* const* d_in, const int* in_sizes, int n_in,
                              void* d_out, int out_size, void* d_ws, size_t ws_size,
                              hipStream_t stream) {
  const float* x      = (const float*)d_in[0];
  const float* ea     = (const float*)d_in[1];
  const int*   eidx   = (const int*)d_in[2];
  const int*   batch  = (const int*)d_in[3];
  const float* node_w = (const float*)d_in[4];
  const float* node_b = (const float*)d_in[5];
  const float* ew1    = (const float*)d_in[6];
  const float* eb1    = (const float*)d_in[7];
  const float* ew2    = (const float*)d_in[8];
  const float* eb2    = (const float*)d_in[9];
  const float* cw1    = (const float*)d_in[10];
  const float* cb1    = (const float*)d_in[11];
  const float* cw2    = (const float*)d_in[12];
  const float* cb2    = (const float*)d_in[13];
  const float* clw1   = (const float*)d_in[14];
  const float* clb1   = (const float*)d_in[15];
  const float* clw2   = (const float*)d_in[16];
  const float* clb2   = (const float*)d_in[17];
  const float* rw1    = (const float*)d_in[18];
  const float* rb1    = (const float*)d_in[19];
  const float* rw2    = (const float*)d_in[20];
  const float* rb2    = (const float*)d_in[21];
  float* out = (float*)d_out;

  int nN = in_sizes[3];        // 100000
  int nE = in_sizes[2] / 2;    // 640000 (divisible by 128)
  int nG = out_size / 2;       // 2048
  const int* src = eidx;
  const int* dst = eidx + nE;

  int NB = (nN + 255) / 256;
  int bins = NB * 256;

  // ---- workspace (~231 MB) ----
  size_t hN = (size_t)nN * HID;
  size_t gN = (size_t)nG * HID;
  float* g    = (float*)d_ws;                       // gN
  int*   cnts = (int*)(g + gN);                     // nG
  unsigned short* wT   = (unsigned short*)(cnts + nG);  // 7*16384
  unsigned short* h16a = wT + 7 * 16384;            // hN
  unsigned short* h16b = h16a + hN;                 // hN
  int* deg    = (int*)(h16b + hN);                  // bins
  int* cursor = deg + bins;                         // bins
  int* rowptr = cursor + bins;                      // bins
  int* bsum   = rowptr + bins;                      // 512
  int* bsumx  = bsum + 512;                         // 512
  int* src_s  = bsumx + 512;                        // nE
  float* ea_s = (float*)(src_s + nE);               // 3*nE
  unsigned short* e16 = (unsigned short*)(ea_s + (size_t)3 * nE);  // nE*128

  // ---- counting sort of edges by dst (also builds CSR rowptr) ----
  k_zero4<<<(int)((bins / 4 + 255) / 256), 256, 0, stream>>>((float4*)deg, bins / 4);
  k_hist<<<(nE + 255) / 256, 256, 0, stream>>>(dst, deg, nE);
  k_scanA<<<NB, 256, 0, stream>>>(deg, bsum);
  k_scanB<<<1, 512, 0, stream>>>(bsum, bsumx, NB);
  k_scanC<<<NB, 256, 0, stream>>>(deg, bsumx, cursor, rowptr);
  k_scatter<<<(nE + 255) / 256, 256, 0, stream>>>(src, dst, ea, cursor, src_s, ea_s, nE);

  k_prep_w<<<(7 * 16384 + 255) / 256, 256, 0, stream>>>(ew2, cw1, cw2, wT);
  k_edge_gemm<<<nE / 128, 256, 0, stream>>>(ea_s, ew1, eb1, wT, eb2, e16, nE);
  k_node_enc<<<(nN * HID + 255) / 256, 256, 0, stream>>>(x, node_w, node_b, h16a, nN);

  // ping-pong: A->B, B->A, A->B  (final in h16b)
  unsigned short* hin  = h16a;
  unsigned short* hout = h16b;
  for (int l = 0; l < 3; ++l) {
    k_conv_csr<<<(nN + 63) / 64, 256, 0, stream>>>(
        hin, e16, src_s, rowptr,
        wT + (size_t)(1 + l) * 16384, cb1 + (size_t)l * HID,
        wT + (size_t)(4 + l) * 16384, cb2 + (size_t)l * HID, hout, nN);
    unsigned short* t = hin; hin = hout; hout = t;
  }

  k_zero4<<<(int)(((gN + nG) / 4 + 255) / 256), 256, 0, stream>>>((float4*)g, (gN + nG) / 4);
  k_counts<<<(nN + 255) / 256, 256, 0, stream>>>(batch, cnts, nN);
  k_pool2<<<(nN + 127) / 128, 256, 0, stream>>>(hin, batch, g, nN);
  k_head<<<nG, 128, 0, stream>>>(g, cnts, clw1, clb1, clw2, clb2,
                                 rw1, rb1, rw2, rb2, out, nG);
}